// Round 1
// baseline (394.996 us; speedup 1.0000x reference)
//
#include <hip/hip_runtime.h>
#include <math.h>

#define C_DIM 256
#define H_DIM 8
#define L_DIM 4
#define P_DIM 4
#define LQ 5440
#define LEN_IN 5440
#define NB 4

// ---------------- Tiled GEMM: out[M x NC] = A[M x 256] @ W[256 x NC] + bias ----------
// 64x64 block tile, 64 threads (1 wave), 8x8 micro-tile per thread, BK=16.
// A staged transposed in LDS (PAD=68 floats keeps rows 16B-aligned, breaks bank
// conflicts); B staged natural. All fragment reads are ds_read_b128.
// Register prefetch of next k-tile overlaps global loads with FMA work.
template <int NC>
__global__ __launch_bounds__(64, 3) void gemm_tiled(const float* __restrict__ A,
                                                    const float* __restrict__ W,
                                                    const float* __restrict__ bias,
                                                    float* __restrict__ out) {
    constexpr int BM = 64, BN = 64, BK = 16, PAD = 68;
    constexpr int NKT = C_DIM / BK;  // 16
    __shared__ __align__(16) float sA[BK * PAD];  // [k][row] transposed
    __shared__ __align__(16) float sB[BK * BN];   // [k][col]

    const int n0 = blockIdx.x * BN;
    const int row0 = blockIdx.y * BM;
    const int t = threadIdx.x;
    const int tx = t & 7;    // owns cols 8*tx .. 8*tx+7
    const int ty = t >> 3;   // owns rows 8*ty .. 8*ty+7

    // A tile 64x16: 256 float4 slots; slot s: row = s>>2, kk = (s&3)*4
    const int a_row = t >> 2;
    const int a_kk = (t & 3) << 2;
    // B tile 16x64: slot s: kr = s>>4, nn = (s&15)*4
    const int b_kr = t >> 4;
    const int b_nn = (t & 15) << 2;

    const float* Ap = A + (size_t)(row0 + a_row) * C_DIM + a_kk;
    const float* Wp = W + (size_t)b_kr * NC + n0 + b_nn;

    float4 pa[4], pb[4];
#pragma unroll
    for (int i = 0; i < 4; ++i) {
        pa[i] = *(const float4*)(Ap + 16 * i * C_DIM);
        pb[i] = *(const float4*)(Wp + 4 * i * NC);
    }

    float acc[8][8];
#pragma unroll
    for (int i = 0; i < 8; ++i)
#pragma unroll
        for (int j = 0; j < 8; ++j) acc[i][j] = 0.f;

    for (int kt = 0; kt < NKT; ++kt) {
        // stage prefetched regs to LDS
#pragma unroll
        for (int i = 0; i < 4; ++i) {
            const int r = a_row + 16 * i;
            sA[(a_kk + 0) * PAD + r] = pa[i].x;
            sA[(a_kk + 1) * PAD + r] = pa[i].y;
            sA[(a_kk + 2) * PAD + r] = pa[i].z;
            sA[(a_kk + 3) * PAD + r] = pa[i].w;
            *(float4*)&sB[(b_kr + 4 * i) * BN + b_nn] = pb[i];
        }
        __syncthreads();
        // prefetch next k-tile while computing this one
        if (kt + 1 < NKT) {
            const int ko = (kt + 1) * BK;
#pragma unroll
            for (int i = 0; i < 4; ++i) {
                pa[i] = *(const float4*)(Ap + 16 * i * C_DIM + ko);
                pb[i] = *(const float4*)(Wp + (ko + 4 * i) * NC);
            }
        }
#pragma unroll
        for (int k = 0; k < BK; ++k) {
            const float4 a0 = *(const float4*)&sA[k * PAD + 8 * ty];
            const float4 a1 = *(const float4*)&sA[k * PAD + 8 * ty + 4];
            const float4 b0 = *(const float4*)&sB[k * BN + 8 * tx];
            const float4 b1 = *(const float4*)&sB[k * BN + 8 * tx + 4];
            const float av[8] = {a0.x, a0.y, a0.z, a0.w, a1.x, a1.y, a1.z, a1.w};
            const float bv[8] = {b0.x, b0.y, b0.z, b0.w, b1.x, b1.y, b1.z, b1.w};
#pragma unroll
            for (int i = 0; i < 8; ++i)
#pragma unroll
                for (int j = 0; j < 8; ++j) acc[i][j] += av[i] * bv[j];
        }
        __syncthreads();
    }

    const float4 bv0 = *(const float4*)&bias[n0 + 8 * tx];
    const float4 bv1 = *(const float4*)&bias[n0 + 8 * tx + 4];
#pragma unroll
    for (int i = 0; i < 8; ++i) {
        float* orow = out + (size_t)(row0 + 8 * ty + i) * NC + n0 + 8 * tx;
        float4 o0, o1;
        o0.x = acc[i][0] + bv0.x; o0.y = acc[i][1] + bv0.y;
        o0.z = acc[i][2] + bv0.z; o0.w = acc[i][3] + bv0.w;
        o1.x = acc[i][4] + bv1.x; o1.y = acc[i][5] + bv1.y;
        o1.z = acc[i][6] + bv1.z; o1.w = acc[i][7] + bv1.w;
        *(float4*)orow = o0;
        *(float4*)(orow + 4) = o1;
    }
}

// ---------------- Sampling: softmax + bilinear gather + weighted sum ----------------
// One wave (64 threads) per query. Stage 1: 128 (h,l,p) slots, 2 per thread:
// softmax (shfl over 16-lane groups), premultiplied attn*bilinear weights (float4)
// and precomputed row BYTE offsets (int4) stored at [lp*8+h] so stage-2 reads are
// bank-conflict-free. Stage 2: t = h*8+d4; float4 gathers (8 lanes x 16B = 128B
// coalesced per corner) with 4 FMAs per corner.
__global__ __launch_bounds__(64) void sample_kernel(const float* __restrict__ value,   // [N*LEN_IN, C]
                                                    const float* __restrict__ offv,    // [N*LQ, 256]
                                                    const float* __restrict__ logits,  // [N*LQ, 128]
                                                    const float* __restrict__ refpts,  // [N, LQ, L, 2]
                                                    float* __restrict__ tmp) {         // [N*LQ, C]
    const int q = blockIdx.x;  // flattened (n, q)
    const int n = q / LQ;
    const int t = threadIdx.x;

    __shared__ __align__(16) float s_aw[128 * 4];  // [lp*8+h][4] attn-premultiplied weights
    __shared__ __align__(16) int s_of[128 * 4];    // [lp*8+h][4] row byte offsets

#pragma unroll
    for (int s = 0; s < 2; ++s) {
        const int j = t + 64 * s;        // slot = ((h*4+l)*4+p)
        const int l = (j >> 2) & 3;
        const int ww = 64 >> l;
        int st = 0;
        if (l == 1) st = 4096;
        else if (l == 2) st = 5120;
        else if (l == 3) st = 5376;

        const float2 oxy = *(const float2*)&offv[(size_t)q * 256 + 2 * j];
        const float2 rxy = *(const float2*)&refpts[((size_t)q * L_DIM + l) * 2];

        const float fw = (float)ww;
        const float x = fminf(fmaxf(rxy.x + oxy.x, 0.f), 1.f) * fw - 0.5f;
        const float y = fminf(fmaxf(rxy.y + oxy.y, 0.f), 1.f) * fw - 0.5f;
        const int xi = (int)floorf(x);
        const int yi = (int)floorf(y);
        const int x0i = min(max(xi, 0), ww - 1);
        const int x1i = min(max(xi + 1, 0), ww - 1);
        const int y0i = min(max(yi, 0), ww - 1);
        const int y1i = min(max(yi + 1, 0), ww - 1);
        const float wx0 = (float)x1i - x, wx1 = x - (float)x0i;
        const float wy0 = (float)y1i - y, wy1 = y - (float)y0i;

        // softmax over the 16 (l,p) slots of this head (16-lane aligned groups)
        const float lg = logits[(size_t)q * 128 + j];
        float m = lg;
#pragma unroll
        for (int o = 8; o; o >>= 1) m = fmaxf(m, __shfl_xor(m, o, 16));
        const float e = expf(lg - m);
        float sm = e;
#pragma unroll
        for (int o = 8; o; o >>= 1) sm += __shfl_xor(sm, o, 16);
        const float a = e / sm;

        const int wi = ((j & 15) << 3) | (j >> 4);  // lp*8 + h
        s_aw[wi * 4 + 0] = a * (wx0 * wy0);         // (y0,x0)
        s_aw[wi * 4 + 1] = a * (wx0 * wy1);         // (y1,x0)
        s_aw[wi * 4 + 2] = a * (wx1 * wy0);         // (y0,x1)
        s_aw[wi * 4 + 3] = a * (wx1 * wy1);         // (y1,x1)
        s_of[wi * 4 + 0] = (st + y0i * ww + x0i) << 10;  // row * 256 floats * 4B
        s_of[wi * 4 + 1] = (st + y1i * ww + x0i) << 10;
        s_of[wi * 4 + 2] = (st + y0i * ww + x1i) << 10;
        s_of[wi * 4 + 3] = (st + y1i * ww + x1i) << 10;
    }
    __syncthreads();

    const int h = t >> 3, d4 = t & 7;
    const char* vb = (const char*)value + (size_t)n * LEN_IN * C_DIM * 4 + (size_t)((h * 8 + d4) * 16);
    float4 acc;
    acc.x = 0.f; acc.y = 0.f; acc.z = 0.f; acc.w = 0.f;
#pragma unroll
    for (int lp = 0; lp < 16; ++lp) {
        const int wi = (lp << 3) | h;
        const float4 aw = *(const float4*)&s_aw[wi * 4];
        const int4 of = *(const int4*)&s_of[wi * 4];
        const float4 v0 = *(const float4*)(vb + of.x);
        const float4 v1 = *(const float4*)(vb + of.y);
        const float4 v2 = *(const float4*)(vb + of.z);
        const float4 v3 = *(const float4*)(vb + of.w);
        acc.x += aw.x * v0.x + aw.y * v1.x + aw.z * v2.x + aw.w * v3.x;
        acc.y += aw.x * v0.y + aw.y * v1.y + aw.z * v2.y + aw.w * v3.y;
        acc.z += aw.x * v0.z + aw.y * v1.z + aw.z * v2.z + aw.w * v3.z;
        acc.w += aw.x * v0.w + aw.y * v1.w + aw.z * v2.w + aw.w * v3.w;
    }
    *(float4*)((char*)tmp + (size_t)q * C_DIM * 4 + (size_t)((h * 8 + d4) * 16)) = acc;
}

extern "C" void kernel_launch(void* const* d_in, const int* in_sizes, int n_in,
                              void* d_out, int out_size, void* d_ws, size_t ws_size,
                              hipStream_t stream) {
    const float* query         = (const float*)d_in[0];
    const float* refpts        = (const float*)d_in[1];
    const float* input_flatten = (const float*)d_in[2];
    // d_in[3] = input_spatial_shapes, d_in[4] = input_level_start_index (static, hardcoded)
    const float* w_off  = (const float*)d_in[5];
    const float* b_off  = (const float*)d_in[6];
    const float* w_attn = (const float*)d_in[7];
    const float* b_attn = (const float*)d_in[8];
    const float* w_val  = (const float*)d_in[9];
    const float* b_val  = (const float*)d_in[10];
    const float* w_out  = (const float*)d_in[11];
    const float* b_out  = (const float*)d_in[12];
    float* out = (float*)d_out;

    float* ws = (float*)d_ws;
    const size_t n_rows = (size_t)NB * LQ;           // 21760
    float* value_ws = ws;                            // 21760*256
    float* offv_ws  = value_ws + n_rows * 256;       // 21760*256
    float* logit_ws = offv_ws + n_rows * 256;        // 21760*128
    float* tmp_ws   = logit_ws + n_rows * 128;       // 21760*256

    const int M = NB * LQ;  // 21760 = 340 * 64

    dim3 g256(C_DIM / 64, M / 64);   // x = n-tile fastest -> A tile reused in L2
    dim3 g128(128 / 64, M / 64);

    gemm_tiled<256><<<g256, 64, 0, stream>>>(input_flatten, w_val, b_val, value_ws);
    gemm_tiled<256><<<g256, 64, 0, stream>>>(query, w_off, b_off, offv_ws);
    gemm_tiled<128><<<g128, 64, 0, stream>>>(query, w_attn, b_attn, logit_ws);
    sample_kernel<<<M, 64, 0, stream>>>(value_ws, offv_ws, logit_ws, refpts, tmp_ws);
    gemm_tiled<256><<<g256, 64, 0, stream>>>(tmp_ws, w_out, b_out, out);
}

// Round 2
// 324.156 us; speedup vs baseline: 1.2185x; 1.2185x over previous
//
#include <hip/hip_runtime.h>
#include <math.h>

#define C_DIM 256
#define H_DIM 8
#define L_DIM 4
#define P_DIM 4
#define LQ 5440
#define LEN_IN 5440
#define NB 4

// ---------------- Split-K GEMM: out[M x NC] = A[M x 256] @ W[256 x NC] + bias --------
// 64x64 tile, 256 threads (4 waves). K=256 is split across waves: per 64-wide K-tile,
// wave w consumes k-slice [w*16, w*16+16). Each LANE owns an 8x8 micro-tile
// (2 FLOP per LDS byte). A staged as float4-along-k with XOR swizzle k4^(row>>3)
// (conflict-free reads AND writes); B staged [k][col] (2-way reads = free).
// Epilogue: 4-round cross-wave reduction via [wave][j][lane] LDS buffer.
template <int NC>
__global__ __launch_bounds__(256, 2) void gemm_splitk(const float* __restrict__ A,
                                                      const float* __restrict__ W,
                                                      const float* __restrict__ bias,
                                                      float* __restrict__ out) {
    __shared__ float4 sA4[64][16];      // [row][k4 ^ (row>>3)] : A[row0+row][kt*64+4*k4 ..+3]
    __shared__ float  sB[64][64];       // [k][col]
    __shared__ float4 red4[4][4][64];   // [wave][j][lane] reduction buffer

    const int n0 = blockIdx.x * 64;
    const int row0 = blockIdx.y * 64;
    const int t = threadIdx.x;
    const int w = t >> 6;       // wave 0..3
    const int lane = t & 63;
    const int lr = lane >> 3;   // micro-tile row group (8 rows)
    const int lc = lane & 7;    // micro-tile col group (8 cols)

    // staging slots
    const int srow = t >> 4;          // A row 0..15 (+16i)
    const int sk4 = t & 15;           // A k4 slot
    const int bk = t >> 4;            // B k-row 0..15 (+16i)
    const int bn = (t & 15) << 2;     // B col 0..60

    const float* Ap = A + (size_t)(row0 + srow) * C_DIM + 4 * sk4;
    const float* Wp = W + (size_t)bk * NC + n0 + bn;

    float4 pa[4], pb[4];
#pragma unroll
    for (int i = 0; i < 4; ++i) {
        pa[i] = *(const float4*)(Ap + (size_t)16 * i * C_DIM);
        pb[i] = *(const float4*)(Wp + (size_t)16 * i * NC);
    }

    float4 acc0[8], acc1[8];
#pragma unroll
    for (int r = 0; r < 8; ++r) {
        acc0[r].x = 0.f; acc0[r].y = 0.f; acc0[r].z = 0.f; acc0[r].w = 0.f;
        acc1[r].x = 0.f; acc1[r].y = 0.f; acc1[r].z = 0.f; acc1[r].w = 0.f;
    }

    for (int kt = 0; kt < 4; ++kt) {
        if (kt) __syncthreads();
#pragma unroll
        for (int i = 0; i < 4; ++i) {
            const int rr = srow + 16 * i;
            sA4[rr][sk4 ^ (rr >> 3)] = pa[i];
            *(float4*)&sB[bk + 16 * i][bn] = pb[i];
        }
        __syncthreads();
        if (kt < 3) {
#pragma unroll
            for (int i = 0; i < 4; ++i) {
                pa[i] = *(const float4*)(Ap + (size_t)16 * i * C_DIM + (kt + 1) * 64);
                pb[i] = *(const float4*)(Wp + (size_t)(16 * i + (kt + 1) * 64) * NC);
            }
        }
#pragma unroll
        for (int g = 0; g < 4; ++g) {
            const int k4g = (w << 2) + g;   // this wave's k4 index (0..15)
            float4 a[8];
#pragma unroll
            for (int r = 0; r < 8; ++r) a[r] = sA4[8 * lr + r][k4g ^ lr];
#pragma unroll
            for (int kk = 0; kk < 4; ++kk) {
                const float4 b0 = *(const float4*)&sB[4 * k4g + kk][8 * lc];
                const float4 b1 = *(const float4*)&sB[4 * k4g + kk][8 * lc + 4];
#pragma unroll
                for (int r = 0; r < 8; ++r) {
                    const float av = (kk == 0) ? a[r].x : (kk == 1) ? a[r].y
                                   : (kk == 2) ? a[r].z : a[r].w;
                    acc0[r].x += av * b0.x; acc0[r].y += av * b0.y;
                    acc0[r].z += av * b0.z; acc0[r].w += av * b0.w;
                    acc1[r].x += av * b1.x; acc1[r].y += av * b1.y;
                    acc1[r].z += av * b1.z; acc1[r].w += av * b1.w;
                }
            }
        }
    }

    const float4 bv0 = *(const float4*)&bias[n0 + 8 * lc];
    const float4 bv1 = *(const float4*)&bias[n0 + 8 * lc + 4];

    // cross-wave reduction: quarter q = micro-tile rows 2q, 2q+1; finalized by wave q
#pragma unroll
    for (int q = 0; q < 4; ++q) {
        __syncthreads();
        red4[w][0][lane] = acc0[2 * q];
        red4[w][1][lane] = acc1[2 * q];
        red4[w][2][lane] = acc0[2 * q + 1];
        red4[w][3][lane] = acc1[2 * q + 1];
        __syncthreads();
        if (w == q) {
            float4 s[4];
#pragma unroll
            for (int j = 0; j < 4; ++j) {
                const float4 x0 = red4[0][j][lane];
                const float4 x1 = red4[1][j][lane];
                const float4 x2 = red4[2][j][lane];
                const float4 x3 = red4[3][j][lane];
                s[j].x = x0.x + x1.x + x2.x + x3.x;
                s[j].y = x0.y + x1.y + x2.y + x3.y;
                s[j].z = x0.z + x1.z + x2.z + x3.z;
                s[j].w = x0.w + x1.w + x2.w + x3.w;
            }
            const int r0 = row0 + 8 * lr + 2 * q;
            float* o0 = out + (size_t)r0 * NC + n0 + 8 * lc;
            float* o1 = o0 + NC;
            float4 t0, t1, t2, t3;
            t0.x = s[0].x + bv0.x; t0.y = s[0].y + bv0.y; t0.z = s[0].z + bv0.z; t0.w = s[0].w + bv0.w;
            t1.x = s[1].x + bv1.x; t1.y = s[1].y + bv1.y; t1.z = s[1].z + bv1.z; t1.w = s[1].w + bv1.w;
            t2.x = s[2].x + bv0.x; t2.y = s[2].y + bv0.y; t2.z = s[2].z + bv0.z; t2.w = s[2].w + bv0.w;
            t3.x = s[3].x + bv1.x; t3.y = s[3].y + bv1.y; t3.z = s[3].z + bv1.z; t3.w = s[3].w + bv1.w;
            *(float4*)o0 = t0;
            *(float4*)(o0 + 4) = t1;
            *(float4*)o1 = t2;
            *(float4*)(o1 + 4) = t3;
        }
    }
}

// ---------------- Sampling: softmax + bilinear gather + weighted sum ----------------
// One wave (64 threads) per query. Stage 1: 128 (h,l,p) slots, 2 per thread:
// softmax (shfl over 16-lane groups), premultiplied attn*bilinear weights (float4)
// and precomputed row BYTE offsets (int4) stored at [lp*8+h] so stage-2 reads are
// bank-conflict-free. Stage 2: t = h*8+d4; float4 gathers (8 lanes x 16B = 128B
// coalesced per corner) with 4 FMAs per corner.
__global__ __launch_bounds__(64) void sample_kernel(const float* __restrict__ value,   // [N*LEN_IN, C]
                                                    const float* __restrict__ offv,    // [N*LQ, 256]
                                                    const float* __restrict__ logits,  // [N*LQ, 128]
                                                    const float* __restrict__ refpts,  // [N, LQ, L, 2]
                                                    float* __restrict__ tmp) {         // [N*LQ, C]
    const int q = blockIdx.x;  // flattened (n, q)
    const int n = q / LQ;
    const int t = threadIdx.x;

    __shared__ __align__(16) float s_aw[128 * 4];  // [lp*8+h][4] attn-premultiplied weights
    __shared__ __align__(16) int s_of[128 * 4];    // [lp*8+h][4] row byte offsets

#pragma unroll
    for (int s = 0; s < 2; ++s) {
        const int j = t + 64 * s;        // slot = ((h*4+l)*4+p)
        const int l = (j >> 2) & 3;
        const int ww = 64 >> l;
        int st = 0;
        if (l == 1) st = 4096;
        else if (l == 2) st = 5120;
        else if (l == 3) st = 5376;

        const float2 oxy = *(const float2*)&offv[(size_t)q * 256 + 2 * j];
        const float2 rxy = *(const float2*)&refpts[((size_t)q * L_DIM + l) * 2];

        const float fw = (float)ww;
        const float x = fminf(fmaxf(rxy.x + oxy.x, 0.f), 1.f) * fw - 0.5f;
        const float y = fminf(fmaxf(rxy.y + oxy.y, 0.f), 1.f) * fw - 0.5f;
        const int xi = (int)floorf(x);
        const int yi = (int)floorf(y);
        const int x0i = min(max(xi, 0), ww - 1);
        const int x1i = min(max(xi + 1, 0), ww - 1);
        const int y0i = min(max(yi, 0), ww - 1);
        const int y1i = min(max(yi + 1, 0), ww - 1);
        const float wx0 = (float)x1i - x, wx1 = x - (float)x0i;
        const float wy0 = (float)y1i - y, wy1 = y - (float)y0i;

        // softmax over the 16 (l,p) slots of this head (16-lane aligned groups)
        const float lg = logits[(size_t)q * 128 + j];
        float m = lg;
#pragma unroll
        for (int o = 8; o; o >>= 1) m = fmaxf(m, __shfl_xor(m, o, 16));
        const float e = expf(lg - m);
        float sm = e;
#pragma unroll
        for (int o = 8; o; o >>= 1) sm += __shfl_xor(sm, o, 16);
        const float a = e / sm;

        const int wi = ((j & 15) << 3) | (j >> 4);  // lp*8 + h
        s_aw[wi * 4 + 0] = a * (wx0 * wy0);         // (y0,x0)
        s_aw[wi * 4 + 1] = a * (wx0 * wy1);         // (y1,x0)
        s_aw[wi * 4 + 2] = a * (wx1 * wy0);         // (y0,x1)
        s_aw[wi * 4 + 3] = a * (wx1 * wy1);         // (y1,x1)
        s_of[wi * 4 + 0] = (st + y0i * ww + x0i) << 10;  // row * 256 floats * 4B
        s_of[wi * 4 + 1] = (st + y1i * ww + x0i) << 10;
        s_of[wi * 4 + 2] = (st + y0i * ww + x1i) << 10;
        s_of[wi * 4 + 3] = (st + y1i * ww + x1i) << 10;
    }
    __syncthreads();

    const int h = t >> 3, d4 = t & 7;
    const char* vb = (const char*)value + (size_t)n * LEN_IN * C_DIM * 4 + (size_t)((h * 8 + d4) * 16);
    float4 acc;
    acc.x = 0.f; acc.y = 0.f; acc.z = 0.f; acc.w = 0.f;
#pragma unroll
    for (int lp = 0; lp < 16; ++lp) {
        const int wi = (lp << 3) | h;
        const float4 aw = *(const float4*)&s_aw[wi * 4];
        const int4 of = *(const int4*)&s_of[wi * 4];
        const float4 v0 = *(const float4*)(vb + of.x);
        const float4 v1 = *(const float4*)(vb + of.y);
        const float4 v2 = *(const float4*)(vb + of.z);
        const float4 v3 = *(const float4*)(vb + of.w);
        acc.x += aw.x * v0.x + aw.y * v1.x + aw.z * v2.x + aw.w * v3.x;
        acc.y += aw.x * v0.y + aw.y * v1.y + aw.z * v2.y + aw.w * v3.y;
        acc.z += aw.x * v0.z + aw.y * v1.z + aw.z * v2.z + aw.w * v3.z;
        acc.w += aw.x * v0.w + aw.y * v1.w + aw.z * v2.w + aw.w * v3.w;
    }
    *(float4*)((char*)tmp + (size_t)q * C_DIM * 4 + (size_t)((h * 8 + d4) * 16)) = acc;
}

extern "C" void kernel_launch(void* const* d_in, const int* in_sizes, int n_in,
                              void* d_out, int out_size, void* d_ws, size_t ws_size,
                              hipStream_t stream) {
    const float* query         = (const float*)d_in[0];
    const float* refpts        = (const float*)d_in[1];
    const float* input_flatten = (const float*)d_in[2];
    // d_in[3] = input_spatial_shapes, d_in[4] = input_level_start_index (static, hardcoded)
    const float* w_off  = (const float*)d_in[5];
    const float* b_off  = (const float*)d_in[6];
    const float* w_attn = (const float*)d_in[7];
    const float* b_attn = (const float*)d_in[8];
    const float* w_val  = (const float*)d_in[9];
    const float* b_val  = (const float*)d_in[10];
    const float* w_out  = (const float*)d_in[11];
    const float* b_out  = (const float*)d_in[12];
    float* out = (float*)d_out;

    float* ws = (float*)d_ws;
    const size_t n_rows = (size_t)NB * LQ;           // 21760
    float* value_ws = ws;                            // 21760*256
    float* offv_ws  = value_ws + n_rows * 256;       // 21760*256
    float* logit_ws = offv_ws + n_rows * 256;        // 21760*128
    float* tmp_ws   = logit_ws + n_rows * 128;       // 21760*256

    const int M = NB * LQ;  // 21760 = 340 * 64

    dim3 g256(C_DIM / 64, M / 64);   // (4, 340)
    dim3 g128(128 / 64, M / 64);     // (2, 340)

    gemm_splitk<256><<<g256, 256, 0, stream>>>(input_flatten, w_val, b_val, value_ws);
    gemm_splitk<256><<<g256, 256, 0, stream>>>(query, w_off, b_off, offv_ws);
    gemm_splitk<128><<<g128, 256, 0, stream>>>(query, w_attn, b_attn, logit_ws);
    sample_kernel<<<M, 64, 0, stream>>>(value_ws, offv_ws, logit_ws, refpts, tmp_ws);
    gemm_splitk<256><<<g256, 256, 0, stream>>>(tmp_ws, w_out, b_out, out);
}

// Round 3
// 233.244 us; speedup vs baseline: 1.6935x; 1.3898x over previous
//
#include <hip/hip_runtime.h>
#include <hip/hip_fp16.h>
#include <math.h>

#define C_DIM 256
#define H_DIM 8
#define L_DIM 4
#define P_DIM 4
#define LQ 5440
#define LEN_IN 5440
#define NB 4
#define M_ROWS (NB * LQ)   // 21760

typedef __attribute__((ext_vector_type(8))) _Float16 f16x8;
typedef __attribute__((ext_vector_type(4))) float f32x4;

__device__ __forceinline__ void split_f32(float a, __half& h, __half& l) {
    h = __float2half(a);
    l = __float2half(a - __half2float(h));
}

// ---- activation split: fp32 [M,256] -> hi/lo f16 [M,256] (memory-bound pass) ----
__global__ __launch_bounds__(256) void convert_act(const float* __restrict__ in,
                                                   __half* __restrict__ hi,
                                                   __half* __restrict__ lo) {
    const int i = blockIdx.x * 256 + threadIdx.x;   // one float4 per thread
    const float4 v = ((const float4*)in)[i];
    __half h0, h1, h2, h3, l0, l1, l2, l3;
    split_f32(v.x, h0, l0); split_f32(v.y, h1, l1);
    split_f32(v.z, h2, l2); split_f32(v.w, h3, l3);
    ushort4 uh, ul;
    uh.x = __half_as_ushort(h0); uh.y = __half_as_ushort(h1);
    uh.z = __half_as_ushort(h2); uh.w = __half_as_ushort(h3);
    ul.x = __half_as_ushort(l0); ul.y = __half_as_ushort(l1);
    ul.z = __half_as_ushort(l2); ul.w = __half_as_ushort(l3);
    ((ushort4*)hi)[i] = uh;
    ((ushort4*)lo)[i] = ul;
}

// ---- weight split + transpose: fp32 [256,ncols] -> hi/lo f16 [ncols,256] ----
__global__ __launch_bounds__(256) void convert_wt(const float* __restrict__ w,
                                                  __half* __restrict__ hi,
                                                  __half* __restrict__ lo, int ncols) {
    const int ncol = blockIdx.x;     // output row
    const int k = threadIdx.x;       // output col (coalesced writes)
    const float a = w[(size_t)k * ncols + ncol];
    __half h, l;
    split_f32(a, h, l);
    hi[(size_t)ncol * 256 + k] = h;
    lo[(size_t)ncol * 256 + k] = l;
}

// ---------------- f16x3 MFMA GEMM: out[M x NC] = A[M x 256] @ W^T + bias ------------
// A given as hi/lo f16 [M][256]; W given as hi/lo f16 TRANSPOSED [NC][256].
// BM=BN=128, BK=32, 256 threads = 2x2 waves, each wave owns 64x64 (4x4 frags of
// 16x16x32). fp32 emulated as Ahi*Bhi + Alo*Bhi + Ahi*Blo (3 MFMA).
// LDS [comp][row][32] halfs with XOR chunk swizzle ch^((row>>1)&3): staging writes
// and frag ds_read_b128 both spread uniformly over the 8 bank-quads.
template <int NC>
__global__ __launch_bounds__(256, 2) void gemm_f16x3(const __half* __restrict__ Ahi,
                                                     const __half* __restrict__ Alo,
                                                     const __half* __restrict__ Bhi,
                                                     const __half* __restrict__ Blo,
                                                     const float* __restrict__ bias,
                                                     float* __restrict__ outp) {
    __shared__ __align__(16) __half sA[2][128][32];
    __shared__ __align__(16) __half sB[2][128][32];

    const int n0 = blockIdx.x * 128;
    const int row0 = blockIdx.y * 128;
    const int t = threadIdx.x;
    const int w = t >> 6, lane = t & 63;
    const int bm = (w >> 1) * 64, bn = (w & 1) * 64;
    const int fr = lane & 15;   // frag row (A) / col (B) / col (C)
    const int fc = lane >> 4;   // frag k-chunk (0..3); C row group

    // staging: 512 16B-chunks per (matrix, comp); thread t does chunks t and t+256
    const int r1 = t >> 2, c1 = t & 3;
    const int r2 = (t + 256) >> 2, c2 = t & 3;
    const int sw1 = (c1 ^ ((r1 >> 1) & 3)) * 8;   // swizzled half-offset
    const int sw2 = (c2 ^ ((r2 >> 1) & 3)) * 8;

    const size_t ga1 = (size_t)(row0 + r1) * 256 + c1 * 8;
    const size_t ga2 = (size_t)(row0 + r2) * 256 + c2 * 8;
    const size_t gb1 = (size_t)(n0 + r1) * 256 + c1 * 8;
    const size_t gb2 = (size_t)(n0 + r2) * 256 + c2 * 8;

    f32x4 acc[4][4];
#pragma unroll
    for (int m = 0; m < 4; ++m)
#pragma unroll
        for (int n = 0; n < 4; ++n)
#pragma unroll
            for (int r = 0; r < 4; ++r) acc[m][n][r] = 0.f;

    float4 pf[8];
    pf[0] = *(const float4*)(Ahi + ga1);
    pf[1] = *(const float4*)(Ahi + ga2);
    pf[2] = *(const float4*)(Alo + ga1);
    pf[3] = *(const float4*)(Alo + ga2);
    pf[4] = *(const float4*)(Bhi + gb1);
    pf[5] = *(const float4*)(Bhi + gb2);
    pf[6] = *(const float4*)(Blo + gb1);
    pf[7] = *(const float4*)(Blo + gb2);

    for (int kt = 0; kt < 8; ++kt) {
        if (kt) __syncthreads();
        *(float4*)&sA[0][r1][sw1] = pf[0];
        *(float4*)&sA[0][r2][sw2] = pf[1];
        *(float4*)&sA[1][r1][sw1] = pf[2];
        *(float4*)&sA[1][r2][sw2] = pf[3];
        *(float4*)&sB[0][r1][sw1] = pf[4];
        *(float4*)&sB[0][r2][sw2] = pf[5];
        *(float4*)&sB[1][r1][sw1] = pf[6];
        *(float4*)&sB[1][r2][sw2] = pf[7];
        __syncthreads();
        if (kt < 7) {
            const size_t ko = (size_t)(kt + 1) * 32;
            pf[0] = *(const float4*)(Ahi + ga1 + ko);
            pf[1] = *(const float4*)(Ahi + ga2 + ko);
            pf[2] = *(const float4*)(Alo + ga1 + ko);
            pf[3] = *(const float4*)(Alo + ga2 + ko);
            pf[4] = *(const float4*)(Bhi + gb1 + ko);
            pf[5] = *(const float4*)(Bhi + gb2 + ko);
            pf[6] = *(const float4*)(Blo + gb1 + ko);
            pf[7] = *(const float4*)(Blo + gb2 + ko);
        }

        f16x8 bhf[4], blf[4];
#pragma unroll
        for (int n = 0; n < 4; ++n) {
            const int rowb = bn + n * 16 + fr;
            const int swb = (fc ^ ((rowb >> 1) & 3)) * 8;
            bhf[n] = *(const f16x8*)&sB[0][rowb][swb];
            blf[n] = *(const f16x8*)&sB[1][rowb][swb];
        }
#pragma unroll
        for (int m = 0; m < 4; ++m) {
            const int rowa = bm + m * 16 + fr;
            const int swa = (fc ^ ((rowa >> 1) & 3)) * 8;
            const f16x8 ah = *(const f16x8*)&sA[0][rowa][swa];
            const f16x8 al = *(const f16x8*)&sA[1][rowa][swa];
#pragma unroll
            for (int n = 0; n < 4; ++n) {
                acc[m][n] = __builtin_amdgcn_mfma_f32_16x16x32_f16(ah, bhf[n], acc[m][n], 0, 0, 0);
                acc[m][n] = __builtin_amdgcn_mfma_f32_16x16x32_f16(al, bhf[n], acc[m][n], 0, 0, 0);
                acc[m][n] = __builtin_amdgcn_mfma_f32_16x16x32_f16(ah, blf[n], acc[m][n], 0, 0, 0);
            }
        }
    }

    // epilogue: C/D layout col = lane&15, row = (lane>>4)*4 + reg
#pragma unroll
    for (int n = 0; n < 4; ++n) {
        const int col = n0 + bn + n * 16 + fr;
        const float bv = bias[col];
#pragma unroll
        for (int m = 0; m < 4; ++m) {
            const int row = row0 + bm + m * 16 + fc * 4;
#pragma unroll
            for (int r = 0; r < 4; ++r)
                outp[(size_t)(row + r) * NC + col] = acc[m][n][r] + bv;
        }
    }
}

// ---------------- Sampling: softmax + bilinear gather + weighted sum ----------------
// One wave per query; writes result as hi/lo f16 (feeds the final f16x3 GEMM).
__global__ __launch_bounds__(64) void sample_kernel(const float* __restrict__ value,   // [N*LEN_IN, C]
                                                    const float* __restrict__ offv,    // [N*LQ, 256]
                                                    const float* __restrict__ logits,  // [N*LQ, 128]
                                                    const float* __restrict__ refpts,  // [N, LQ, L, 2]
                                                    __half* __restrict__ tmp_hi,       // [N*LQ, C]
                                                    __half* __restrict__ tmp_lo) {
    const int q = blockIdx.x;
    const int n = q / LQ;
    const int t = threadIdx.x;

    __shared__ __align__(16) float s_aw[128 * 4];
    __shared__ __align__(16) int s_of[128 * 4];

#pragma unroll
    for (int s = 0; s < 2; ++s) {
        const int j = t + 64 * s;
        const int l = (j >> 2) & 3;
        const int ww = 64 >> l;
        int st = 0;
        if (l == 1) st = 4096;
        else if (l == 2) st = 5120;
        else if (l == 3) st = 5376;

        const float2 oxy = *(const float2*)&offv[(size_t)q * 256 + 2 * j];
        const float2 rxy = *(const float2*)&refpts[((size_t)q * L_DIM + l) * 2];

        const float fw = (float)ww;
        const float x = fminf(fmaxf(rxy.x + oxy.x, 0.f), 1.f) * fw - 0.5f;
        const float y = fminf(fmaxf(rxy.y + oxy.y, 0.f), 1.f) * fw - 0.5f;
        const int xi = (int)floorf(x);
        const int yi = (int)floorf(y);
        const int x0i = min(max(xi, 0), ww - 1);
        const int x1i = min(max(xi + 1, 0), ww - 1);
        const int y0i = min(max(yi, 0), ww - 1);
        const int y1i = min(max(yi + 1, 0), ww - 1);
        const float wx0 = (float)x1i - x, wx1 = x - (float)x0i;
        const float wy0 = (float)y1i - y, wy1 = y - (float)y0i;

        const float lg = logits[(size_t)q * 128 + j];
        float m = lg;
#pragma unroll
        for (int o = 8; o; o >>= 1) m = fmaxf(m, __shfl_xor(m, o, 16));
        const float e = expf(lg - m);
        float sm = e;
#pragma unroll
        for (int o = 8; o; o >>= 1) sm += __shfl_xor(sm, o, 16);
        const float a = e / sm;

        const int wi = ((j & 15) << 3) | (j >> 4);  // lp*8 + h
        s_aw[wi * 4 + 0] = a * (wx0 * wy0);
        s_aw[wi * 4 + 1] = a * (wx0 * wy1);
        s_aw[wi * 4 + 2] = a * (wx1 * wy0);
        s_aw[wi * 4 + 3] = a * (wx1 * wy1);
        s_of[wi * 4 + 0] = (st + y0i * ww + x0i) << 10;
        s_of[wi * 4 + 1] = (st + y1i * ww + x0i) << 10;
        s_of[wi * 4 + 2] = (st + y0i * ww + x1i) << 10;
        s_of[wi * 4 + 3] = (st + y1i * ww + x1i) << 10;
    }
    __syncthreads();

    const int h = t >> 3, d4 = t & 7;
    const char* vb = (const char*)value + (size_t)n * LEN_IN * C_DIM * 4 + (size_t)((h * 8 + d4) * 16);
    float4 acc;
    acc.x = 0.f; acc.y = 0.f; acc.z = 0.f; acc.w = 0.f;
#pragma unroll
    for (int lp = 0; lp < 16; ++lp) {
        const int wi = (lp << 3) | h;
        const float4 aw = *(const float4*)&s_aw[wi * 4];
        const int4 of = *(const int4*)&s_of[wi * 4];
        const float4 v0 = *(const float4*)(vb + of.x);
        const float4 v1 = *(const float4*)(vb + of.y);
        const float4 v2 = *(const float4*)(vb + of.z);
        const float4 v3 = *(const float4*)(vb + of.w);
        acc.x += aw.x * v0.x + aw.y * v1.x + aw.z * v2.x + aw.w * v3.x;
        acc.y += aw.x * v0.y + aw.y * v1.y + aw.z * v2.y + aw.w * v3.y;
        acc.z += aw.x * v0.z + aw.y * v1.z + aw.z * v2.z + aw.w * v3.z;
        acc.w += aw.x * v0.w + aw.y * v1.w + aw.z * v2.w + aw.w * v3.w;
    }

    __half h0, h1, h2, h3, l0, l1, l2, l3;
    split_f32(acc.x, h0, l0); split_f32(acc.y, h1, l1);
    split_f32(acc.z, h2, l2); split_f32(acc.w, h3, l3);
    ushort4 uh, ul;
    uh.x = __half_as_ushort(h0); uh.y = __half_as_ushort(h1);
    uh.z = __half_as_ushort(h2); uh.w = __half_as_ushort(h3);
    ul.x = __half_as_ushort(l0); ul.y = __half_as_ushort(l1);
    ul.z = __half_as_ushort(l2); ul.w = __half_as_ushort(l3);
    const size_t base = (size_t)q * 256 + (size_t)((h * 8 + d4) * 4);
    *(ushort4*)&tmp_hi[base] = uh;
    *(ushort4*)&tmp_lo[base] = ul;
}

extern "C" void kernel_launch(void* const* d_in, const int* in_sizes, int n_in,
                              void* d_out, int out_size, void* d_ws, size_t ws_size,
                              hipStream_t stream) {
    const float* query         = (const float*)d_in[0];
    const float* refpts        = (const float*)d_in[1];
    const float* input_flatten = (const float*)d_in[2];
    // d_in[3] = input_spatial_shapes, d_in[4] = input_level_start_index (static, hardcoded)
    const float* w_off  = (const float*)d_in[5];
    const float* b_off  = (const float*)d_in[6];
    const float* w_attn = (const float*)d_in[7];
    const float* b_attn = (const float*)d_in[8];
    const float* w_val  = (const float*)d_in[9];
    const float* b_val  = (const float*)d_in[10];
    const float* w_out  = (const float*)d_in[11];
    const float* b_out  = (const float*)d_in[12];
    float* out = (float*)d_out;

    const size_t nr = (size_t)M_ROWS;           // 21760
    float* ws = (float*)d_ws;
    float* value_ws = ws;                        // fp32 [M,256]
    float* offv_ws  = value_ws + nr * 256;       // fp32 [M,256]
    float* logit_ws = offv_ws + nr * 256;        // fp32 [M,128]
    __half* q_hi = (__half*)(logit_ws + nr * 128);  // f16 [M,256] (reused as tmp_hi)
    __half* q_lo = q_hi + nr * 256;                 // f16 [M,256] (reused as tmp_lo)
    __half* wv_hi = q_lo + nr * 256;             // weights hi/lo, transposed [NC][256]
    __half* wv_lo = wv_hi + 256 * 256;
    __half* wo_hi = wv_lo + 256 * 256;
    __half* wo_lo = wo_hi + 256 * 256;
    __half* wa_hi = wo_lo + 256 * 256;
    __half* wa_lo = wa_hi + 128 * 256;
    __half* wt_hi = wa_lo + 128 * 256;
    __half* wt_lo = wt_hi + 256 * 256;
    // input_flatten halves live in d_out (scratch until the final GEMM overwrites it)
    __half* if_hi = (__half*)d_out;
    __half* if_lo = if_hi + nr * 256;

    const int NV4 = (int)(nr * 256 / 4);         // float4 count per activation

    convert_act<<<NV4 / 256, 256, 0, stream>>>(input_flatten, if_hi, if_lo);
    convert_act<<<NV4 / 256, 256, 0, stream>>>(query, q_hi, q_lo);
    convert_wt<<<256, 256, 0, stream>>>(w_val, wv_hi, wv_lo, 256);
    convert_wt<<<256, 256, 0, stream>>>(w_off, wo_hi, wo_lo, 256);
    convert_wt<<<128, 256, 0, stream>>>(w_attn, wa_hi, wa_lo, 128);
    convert_wt<<<256, 256, 0, stream>>>(w_out, wt_hi, wt_lo, 256);

    dim3 g256(2, M_ROWS / 128);   // (2, 170)
    dim3 g128(1, M_ROWS / 128);

    gemm_f16x3<256><<<g256, 256, 0, stream>>>(if_hi, if_lo, wv_hi, wv_lo, b_val, value_ws);
    gemm_f16x3<256><<<g256, 256, 0, stream>>>(q_hi, q_lo, wo_hi, wo_lo, b_off, offv_ws);
    gemm_f16x3<128><<<g128, 256, 0, stream>>>(q_hi, q_lo, wa_hi, wa_lo, b_attn, logit_ws);

    // sample overwrites q_hi/q_lo with tmp hi/lo (q no longer needed)
    sample_kernel<<<M_ROWS, 64, 0, stream>>>(value_ws, offv_ws, logit_ws, refpts, q_hi, q_lo);

    gemm_f16x3<256><<<g256, 256, 0, stream>>>(q_hi, q_lo, wt_hi, wt_lo, b_out, out);
}